// Round 3
// baseline (1507.306 us; speedup 1.0000x reference)
//
#include <hip/hip_runtime.h>

// RelativeAxialAttention on MI355X (gfx950). Dtype-robust recompute design.
// K=48, G=8, DK=8, DV=16, CIN=64, B = 2304, samples per kv/q channel = B*H = 110592.
// Float tensors may be f32 or bf16 in memory -> detected at runtime on device
// (flag in workspace); internal compute f32.
//
// Math shortcuts:
//  * kv/q BatchNorm folded into GEMM weights via x-gram (y=Wx => mean=W.mu, E[y^2]=W M W^T).
//  * sim BN: mean & beta are per-(t,g) constants => softmax-invariant; only scales needed.
//  * out BN applied inside attention pass B; q/k/v recomputed per consumer.
// Workspace need: ~236 KB base; optional 56.6 MB f32 `fin` staging if ws_size allows.

typedef unsigned short u16;

#define N_S 110592
#define N_B 2304

__device__ __forceinline__ float b2f(u16 v) {
    return __builtin_bit_cast(float, ((unsigned)v) << 16);
}
__device__ __forceinline__ u16 f2b(float f) {
    unsigned u = __builtin_bit_cast(unsigned, f);
    u = (u + 0x7FFFu + ((u >> 16) & 1u)) >> 16;
    return (u16)u;
}
// generic load: f32 flag ? float : bf16
__device__ __forceinline__ float ldf(const void* p, int idx, int f32) {
    return f32 ? ((const float*)p)[idx] : b2f(((const u16*)p)[idx]);
}

// ---------------- dtype detection: sample even u16 indices of X ----------------
// bf16 data: nearly all have exponent field in [0x70,0x8F] (|x| ~ N(0,1)).
// f32 data: even u16s are low mantissa halves -> random -> ~12.5% hit.
__global__ void k_detect(const u16* X, int* flag) {
    __shared__ int tot;
    if (threadIdx.x == 0) tot = 0;
    __syncthreads();
    int cnt = 0;
#pragma unroll
    for (int k = 0; k < 8; k++) {
        u16 v = X[(threadIdx.x * 8 + k) * 2];
        int e = (v >> 7) & 0xFF;
        cnt += (e >= 0x70 && e <= 0x8F) ? 1 : 0;
    }
    atomicAdd(&tot, cnt);
    __syncthreads();
    if (threadIdx.x == 0) flag[0] = (tot < 1024) ? 1 : 0;   // 1 = f32
}

// ---------------- zero the atomically-accumulated stats region ----------------
__global__ void k_zero(float* w) {
    for (int i = blockIdx.x * blockDim.x + threadIdx.x; i < 4720; i += gridDim.x * blockDim.x)
        w[i] = 0.0f;
}

// ---------------- build emb tables (bf16; keT pre-transposed) ----------------
__global__ void k_emb(const void* rel, const int* fidx, const int* flag,
                      u16* qe, u16* keT, u16* ve) {
    int f32 = flag[0];
    int t = blockIdx.x * 256 + threadIdx.x;
    if (t >= 2304) return;
    int i = t / 48, j = t % 48;
    int fij = fidx[i * 48 + j];
    int fji = fidx[j * 48 + i];
#pragma unroll
    for (int c = 0; c < 8; c++) {
        qe[c * 2304 + t]  = f2b(ldf(rel, c * 95 + fij, f32));        // q_emb[c][i][j]
        keT[c * 2304 + t] = f2b(ldf(rel, (8 + c) * 95 + fji, f32));  // k_emb[c][j][i]
    }
#pragma unroll
    for (int c = 0; c < 16; c++)
        ve[c * 2304 + t] = f2b(ldf(rel, (16 + c) * 95 + fij, f32));  // v_emb[c][i][j]
}

// ---------------- x gram ----------------
__global__ __launch_bounds__(256) void k_gram(const void* Xv, const int* flag,
                                              float* musum, float* gram) {
    __shared__ float xs[64 * 65];
    int f32 = flag[0];
    int tid = threadIdx.x;
    int cb1 = tid >> 4, cb2 = tid & 15;
    float acc[4][4];
#pragma unroll
    for (int a = 0; a < 4; a++)
#pragma unroll
        for (int b = 0; b < 4; b++) acc[a][b] = 0.0f;
    float mur = 0.0f;
    for (int tile = blockIdx.x; tile < 1728; tile += gridDim.x) {
        int s0 = tile * 64;
        __syncthreads();
#pragma unroll
        for (int r = 0; r < 4; r++) {
            int idx4 = tid + 256 * r;
            int c = idx4 >> 4, sl = (idx4 & 15) * 4;
            if (f32) {
                float4 u = *(const float4*)((const float*)Xv + c * N_S + s0 + sl);
                xs[c * 65 + sl + 0] = u.x; xs[c * 65 + sl + 1] = u.y;
                xs[c * 65 + sl + 2] = u.z; xs[c * 65 + sl + 3] = u.w;
            } else {
                ushort4 u = *(const ushort4*)((const u16*)Xv + c * N_S + s0 + sl);
                xs[c * 65 + sl + 0] = b2f(u.x); xs[c * 65 + sl + 1] = b2f(u.y);
                xs[c * 65 + sl + 2] = b2f(u.z); xs[c * 65 + sl + 3] = b2f(u.w);
            }
        }
        __syncthreads();
        for (int s = 0; s < 64; s++) {
            float av[4], bv[4];
#pragma unroll
            for (int a = 0; a < 4; a++) av[a] = xs[(cb1 + 16 * a) * 65 + s];
#pragma unroll
            for (int b = 0; b < 4; b++) bv[b] = xs[(cb2 + 16 * b) * 65 + s];
#pragma unroll
            for (int a = 0; a < 4; a++)
#pragma unroll
                for (int b = 0; b < 4; b++) acc[a][b] += av[a] * bv[b];
        }
        if (tid < 64) {
            for (int s = 0; s < 64; s++) mur += xs[tid * 65 + s];
        }
    }
#pragma unroll
    for (int a = 0; a < 4; a++)
#pragma unroll
        for (int b = 0; b < 4; b++)
            atomicAdd(&gram[(cb1 + 16 * a) * 64 + (cb2 + 16 * b)], acc[a][b]);
    if (tid < 64) atomicAdd(&musum[tid], mur);
}

// ---------------- fold BN into weights ----------------
__global__ __launch_bounds__(256) void k_fold(const void* Wkv, const void* Wq,
        const void* gkv, const void* bkv, const void* gq, const void* bq,
        const int* flag, const float* musum, const float* gram,
        float* weff, float* beff) {
    int f32 = flag[0];
    int o = threadIdx.x;
    float gam, bet;
    float w[64];
    if (o < 192) {
#pragma unroll
        for (int c = 0; c < 64; c++) w[c] = ldf(Wkv, o * 64 + c, f32);
        gam = ldf(gkv, o, f32); bet = ldf(bkv, o, f32);
    } else {
        int oq = o - 192;
#pragma unroll
        for (int c = 0; c < 64; c++) w[c] = ldf(Wq, oq * 64 + c, f32);
        gam = ldf(gq, oq, f32); bet = ldf(bq, oq, f32);
    }
    const float inv = 1.0f / (float)N_S;
    float mean = 0.0f;
#pragma unroll
    for (int c = 0; c < 64; c++) mean += w[c] * musum[c];
    mean *= inv;
    float e2 = 0.0f;
    for (int c = 0; c < 64; c++) {
        float t = 0.0f;
#pragma unroll
        for (int c2 = 0; c2 < 64; c2++) t += w[c2] * gram[c * 64 + c2];
        e2 += w[c] * t;
    }
    e2 *= inv;
    float var = e2 - mean * mean;
    if (var < 0.0f) var = 0.0f;
    float sc = gam * rsqrtf(var + 1e-5f);
#pragma unroll
    for (int c = 0; c < 64; c++) weff[o * 64 + c] = sc * w[c];
    beff[o] = bet - sc * mean;
}

// ---------------- fused q/k GEMM + sim BN stats, one block per b ----------------
__global__ __launch_bounds__(256) void k_qkstat(const void* Xv, const float* weff, const float* beff,
        const u16* qe, const u16* keT, const void* fqrp, const void* fkrp,
        const int* flag, float* sstat) {
    __shared__ __align__(16) float xs[3072];
    __shared__ __align__(16) float qsh[3072];
    __shared__ __align__(16) float ksh[3072];
    __shared__ float red[48];
    int f32 = flag[0];
    int b = blockIdx.x, tid = threadIdx.x;
    for (int idx = tid; idx < 3072; idx += 256) {
        int c = idx / 48, h = idx % 48;
        xs[idx] = ldf(Xv, c * N_S + h * 2304 + b, f32);
    }
    if (tid < 48) red[tid] = 0.0f;
    __syncthreads();
    {   // GEMM: 128 rows (q:0-63, k:64-127), 2 threads per row
        int r = tid >> 1, half = tid & 1;
        int o; float* dst;
        if (r < 64) { o = 192 + r; dst = qsh + r * 48; }
        else { int rk = r - 64; o = (rk >> 3) * 24 + (rk & 7); dst = ksh + rk * 48; }
        float wr[64];
        const float4* wrow = (const float4*)(weff + o * 64);
#pragma unroll
        for (int c4 = 0; c4 < 16; c4++) {
            float4 t4 = wrow[c4];
            wr[c4 * 4 + 0] = t4.x; wr[c4 * 4 + 1] = t4.y; wr[c4 * 4 + 2] = t4.z; wr[c4 * 4 + 3] = t4.w;
        }
        float bias = beff[o];
        int h0 = half * 24;
#pragma unroll
        for (int hb = 0; hb < 3; hb++) {
            float acc[8];
#pragma unroll
            for (int u = 0; u < 8; u++) acc[u] = bias;
#pragma unroll
            for (int c = 0; c < 64; c++) {
                float wv = wr[c];
                const float4* xp = (const float4*)(xs + c * 48 + h0 + hb * 8);
                float4 x0 = xp[0], x1 = xp[1];
                acc[0] += wv * x0.x; acc[1] += wv * x0.y; acc[2] += wv * x0.z; acc[3] += wv * x0.w;
                acc[4] += wv * x1.x; acc[5] += wv * x1.y; acc[6] += wv * x1.z; acc[7] += wv * x1.w;
            }
            *(float4*)(dst + h0 + hb * 8)     = make_float4(acc[0], acc[1], acc[2], acc[3]);
            *(float4*)(dst + h0 + hb * 8 + 4) = make_float4(acc[4], acc[5], acc[6], acc[7]);
        }
    }
    __syncthreads();
    float fqr = ldf(fqrp, 0, f32), fkr = ldf(fkrp, 0, f32);
    float sum[24], sq[24];
#pragma unroll
    for (int k = 0; k < 24; k++) { sum[k] = 0.0f; sq[k] = 0.0f; }
    for (int r = 0; r < 3; r++) {
        int chunk = tid + 256 * r;
        if (chunk >= 576) break;
        int i = chunk / 12, j0 = (chunk % 12) * 4;
        float qv[8][4], kv[8][4];
#pragma unroll
        for (int c = 0; c < 8; c++) {
            ushort4 uq = *(const ushort4*)(qe + c * 2304 + i * 48 + j0);
            ushort4 uk = *(const ushort4*)(keT + c * 2304 + i * 48 + j0);
            qv[c][0] = b2f(uq.x); qv[c][1] = b2f(uq.y); qv[c][2] = b2f(uq.z); qv[c][3] = b2f(uq.w);
            kv[c][0] = b2f(uk.x); kv[c][1] = b2f(uk.y); kv[c][2] = b2f(uk.z); kv[c][3] = b2f(uk.w);
        }
#pragma unroll
        for (int g = 0; g < 8; g++) {
            float zq[4] = {0,0,0,0}, zr[4] = {0,0,0,0}, zk[4] = {0,0,0,0};
#pragma unroll
            for (int c = 0; c < 8; c++) {
                float qi = qsh[(g * 8 + c) * 48 + i];
                float4 kk = *(const float4*)(ksh + (g * 8 + c) * 48 + j0);
                zq[0] += qi * kk.x; zq[1] += qi * kk.y; zq[2] += qi * kk.z; zq[3] += qi * kk.w;
                zr[0] += qi * qv[c][0]; zr[1] += qi * qv[c][1]; zr[2] += qi * qv[c][2]; zr[3] += qi * qv[c][3];
                zk[0] += kk.x * kv[c][0]; zk[1] += kk.y * kv[c][1]; zk[2] += kk.z * kv[c][2]; zk[3] += kk.w * kv[c][3];
            }
#pragma unroll
            for (int u = 0; u < 4; u++) {
                float a = zq[u];        sum[g] += a;       sq[g] += a * a;
                float r1 = zr[u] * fqr; sum[8 + g] += r1;  sq[8 + g] += r1 * r1;
                float r2 = zk[u] * fkr; sum[16 + g] += r2; sq[16 + g] += r2 * r2;
            }
        }
    }
#pragma unroll
    for (int k = 0; k < 24; k++) {
        float s = sum[k], q = sq[k];
        for (int off = 32; off >= 1; off >>= 1) { s += __shfl_xor(s, off); q += __shfl_xor(q, off); }
        if ((tid & 63) == 0) { atomicAdd(&red[k], s); atomicAdd(&red[24 + k], q); }
    }
    __syncthreads();
    if (tid < 48) atomicAdd(&sstat[tid], red[tid]);
}

__global__ void k_simcoef(const float* sstat, const void* gsim, const int* flag, float* scoef) {
    int ch = threadIdx.x;
    if (ch >= 24) return;
    const float n = 2304.0f * 2304.0f;   // B*H*H
    float mean = sstat[ch] / n;
    float var = sstat[24 + ch] / n - mean * mean;
    if (var < 0.0f) var = 0.0f;
    scoef[ch] = ldf(gsim, ch, flag[0]) * rsqrtf(var + 1e-5f);
}

// ---------------- fused attention, one block per b ----------------
// mode 0: accumulate out-BN stats. mode 1: write fin[b][128][48] (f32). mode 2: scattered direct out.
__global__ __launch_bounds__(256) void k_attn(const void* Xv, const float* weff, const float* beff,
        const u16* qe, const u16* keT, const u16* ve,
        const float* scoef, const float* ocoef,
        const void* fqrp, const void* fkrp, const void* fsvp, const void* fsvep,
        const int* flag, float* ostat, float* fin, void* outp, int mode) {
    __shared__ __align__(16) float zx[3072];   // x staging, then z[48][52]
    __shared__ __align__(16) float qsh[3072];
    __shared__ __align__(16) float ksh[3072];
    __shared__ __align__(16) float vsh[6144];
    __shared__ float osl[512];
    int f32 = flag[0];
    int b = blockIdx.x, tid = threadIdx.x;
    for (int idx = tid; idx < 3072; idx += 256) {
        int c = idx / 48, h = idx % 48;
        zx[idx] = ldf(Xv, c * N_S + h * 2304 + b, f32);
    }
    __syncthreads();
    {   // GEMM: 256 rows (q:0-63, k:64-127, v:128-255), 1 thread per row
        int o; float* dst;
        if (tid < 64)       { o = 192 + tid; dst = qsh + tid * 48; }
        else if (tid < 128) { int rk = tid - 64; o = (rk >> 3) * 24 + (rk & 7); dst = ksh + rk * 48; }
        else                { int rv = tid - 128; o = (rv >> 4) * 24 + 8 + (rv & 15); dst = vsh + rv * 48; }
        float wr[64];
        const float4* wrow = (const float4*)(weff + o * 64);
#pragma unroll
        for (int c4 = 0; c4 < 16; c4++) {
            float4 t4 = wrow[c4];
            wr[c4 * 4 + 0] = t4.x; wr[c4 * 4 + 1] = t4.y; wr[c4 * 4 + 2] = t4.z; wr[c4 * 4 + 3] = t4.w;
        }
        float bias = beff[o];
#pragma unroll
        for (int hb = 0; hb < 6; hb++) {
            float acc[8];
#pragma unroll
            for (int u = 0; u < 8; u++) acc[u] = bias;
#pragma unroll
            for (int c = 0; c < 64; c++) {
                float wv = wr[c];
                const float4* xp = (const float4*)(zx + c * 48 + hb * 8);
                float4 x0 = xp[0], x1 = xp[1];
                acc[0] += wv * x0.x; acc[1] += wv * x0.y; acc[2] += wv * x0.z; acc[3] += wv * x0.w;
                acc[4] += wv * x1.x; acc[5] += wv * x1.y; acc[6] += wv * x1.z; acc[7] += wv * x1.w;
            }
            *(float4*)(dst + hb * 8)     = make_float4(acc[0], acc[1], acc[2], acc[3]);
            *(float4*)(dst + hb * 8 + 4) = make_float4(acc[4], acc[5], acc[6], acc[7]);
        }
    }
    __syncthreads();
    float fqr = ldf(fqrp, 0, f32), fkr = ldf(fkrp, 0, f32);
    float fsv = ldf(fsvp, 0, f32), fsve = ldf(fsvep, 0, f32);
    float* z = zx;
    for (int g = 0; g < 8; g++) {
        float c0 = scoef[g], c1 = scoef[8 + g], c2 = scoef[16 + g];
        // logits
        for (int r = 0; r < 3; r++) {
            int chunk = tid + 256 * r;
            if (chunk >= 576) break;
            int i = chunk / 12, j0 = (chunk % 12) * 4;
            float zq[4] = {0,0,0,0}, zr[4] = {0,0,0,0}, zk[4] = {0,0,0,0};
#pragma unroll
            for (int c = 0; c < 8; c++) {
                ushort4 uq = *(const ushort4*)(qe + c * 2304 + i * 48 + j0);
                ushort4 uk = *(const ushort4*)(keT + c * 2304 + i * 48 + j0);
                float qi = qsh[(g * 8 + c) * 48 + i];
                float4 kk = *(const float4*)(ksh + (g * 8 + c) * 48 + j0);
                zq[0] += qi * kk.x; zq[1] += qi * kk.y; zq[2] += qi * kk.z; zq[3] += qi * kk.w;
                zr[0] += qi * b2f(uq.x); zr[1] += qi * b2f(uq.y); zr[2] += qi * b2f(uq.z); zr[3] += qi * b2f(uq.w);
                zk[0] += kk.x * b2f(uk.x); zk[1] += kk.y * b2f(uk.y); zk[2] += kk.z * b2f(uk.z); zk[3] += kk.w * b2f(uk.w);
            }
            float4 o4;
            o4.x = c0 * zq[0] + c1 * (fqr * zr[0]) + c2 * (fkr * zk[0]);
            o4.y = c0 * zq[1] + c1 * (fqr * zr[1]) + c2 * (fkr * zk[1]);
            o4.z = c0 * zq[2] + c1 * (fqr * zr[2]) + c2 * (fkr * zk[2]);
            o4.w = c0 * zq[3] + c1 * (fqr * zr[3]) + c2 * (fkr * zk[3]);
            *(float4*)(z + i * 52 + j0) = o4;
        }
        __syncthreads();
        {   // softmax: one wave per 12 rows
            int wv = tid >> 6, lane = tid & 63;
            for (int rr = 0; rr < 12; rr++) {
                int i = wv * 12 + rr;
                float val = (lane < 48) ? z[i * 52 + lane] : -1e30f;
                float m = val;
                for (int off = 32; off >= 1; off >>= 1) m = fmaxf(m, __shfl_xor(m, off));
                float e = (lane < 48) ? __expf(val - m) : 0.0f;
                float s = e;
                for (int off = 32; off >= 1; off >>= 1) s += __shfl_xor(s, off);
                if (lane < 48) z[i * 52 + lane] = e / s;
            }
        }
        __syncthreads();
        {   // sv / sve
            int c = tid >> 4, u = tid & 15;
            int ch2 = g * 32 + c * 2;
            float oc0 = 0, oc1 = 0, osh = 0;
            if (mode != 0) {
                oc0 = ocoef[ch2 * 2]; oc1 = ocoef[(ch2 + 1) * 2];
                osh = ocoef[ch2 * 2 + 1] + ocoef[(ch2 + 1) * 2 + 1];
            }
            float sumA = 0, sqA = 0, sumB = 0, sqB = 0;
#pragma unroll
            for (int r = 0; r < 3; r++) {
                int i = u + 16 * r;
                float sv = 0.0f, se = 0.0f;
#pragma unroll
                for (int j4 = 0; j4 < 12; j4++) {
                    float4 sm = *(const float4*)(z + i * 52 + j4 * 4);
                    float4 vv = *(const float4*)(vsh + (g * 16 + c) * 48 + j4 * 4);
                    ushort4 veu = *(const ushort4*)(ve + c * 2304 + i * 48 + j4 * 4);
                    sv += sm.x * vv.x + sm.y * vv.y + sm.z * vv.z + sm.w * vv.w;
                    se += sm.x * b2f(veu.x) + sm.y * b2f(veu.y) + sm.z * b2f(veu.z) + sm.w * b2f(veu.w);
                }
                float a = sv * fsv, bb = se * fsve;
                if (mode == 0) {
                    sumA += a; sqA += a * a; sumB += bb; sqB += bb * bb;
                } else {
                    float outv = a * oc0 + bb * oc1 + osh;
                    if (mode == 1) fin[(b * 128 + g * 16 + c) * 48 + i] = outv;
                    else {
                        int oidx = (g * 16 + c) * N_S + i * 2304 + b;
                        if (f32) ((float*)outp)[oidx] = outv;
                        else     ((u16*)outp)[oidx] = f2b(outv);
                    }
                }
            }
            if (mode == 0) {
                for (int off = 1; off <= 8; off <<= 1) {
                    sumA += __shfl_xor(sumA, off); sqA += __shfl_xor(sqA, off);
                    sumB += __shfl_xor(sumB, off); sqB += __shfl_xor(sqB, off);
                }
                if (u == 0) {
                    int base = ch2 * 2;
                    osl[base + 0] = sumA; osl[base + 1] = sqA;
                    osl[base + 2] = sumB; osl[base + 3] = sqB;
                }
            }
        }
        __syncthreads();
    }
    if (mode == 0) {
        atomicAdd(&ostat[tid], osl[tid]);
        atomicAdd(&ostat[tid + 256], osl[tid + 256]);
    }
}

__global__ void k_outcoef(const float* ostat, const void* gout, const void* bout,
                          const int* flag, float* ocoef) {
    int f32 = flag[0];
    int o = threadIdx.x;   // 256
    const float n = 110592.0f;
    float mean = ostat[o * 2] / n;
    float var = ostat[o * 2 + 1] / n - mean * mean;
    if (var < 0.0f) var = 0.0f;
    float sc = ldf(gout, o, f32) * rsqrtf(var + 1e-5f);
    ocoef[o * 2] = sc;
    ocoef[o * 2 + 1] = ldf(bout, o, f32) - mean * sc;
}

// ---------------- transpose fin[b][128][48] -> out[ch][h][b] ----------------
__global__ __launch_bounds__(256) void k_trans(const float* fin, const int* flag, void* outp) {
    __shared__ float tile[48 * 49];
    int f32 = flag[0];
    int ch = blockIdx.x, w = blockIdx.y, tid = threadIdx.x;
#pragma unroll
    for (int r = 0; r < 9; r++) {
        int idx = tid + 256 * r;
        int d = idx / 48, h = idx % 48;
        tile[d * 49 + h] = fin[((w * 48 + d) * 128 + ch) * 48 + h];
    }
    __syncthreads();
#pragma unroll
    for (int r = 0; r < 9; r++) {
        int idx = tid + 256 * r;
        int h = idx / 48, d = idx % 48;
        float v = tile[d * 49 + h];
        int oidx = ch * N_S + h * 2304 + w * 48 + d;
        if (f32) ((float*)outp)[oidx] = v;
        else     ((u16*)outp)[oidx] = f2b(v);
    }
}

extern "C" void kernel_launch(void* const* d_in, const int* in_sizes, int n_in,
                              void* d_out, int out_size, void* d_ws, size_t ws_size,
                              hipStream_t stream) {
    const void* X    = d_in[0];
    const void* Wkv  = d_in[1];
    const void* Wq   = d_in[2];
    const void* gkv  = d_in[3];
    const void* bkv  = d_in[4];
    const void* gq   = d_in[5];
    const void* bq   = d_in[6];
    const void* gsim = d_in[7];
    // d_in[8] (b_sim) unused: additive per-channel constant, softmax-invariant.
    const void* gout = d_in[9];
    const void* bout = d_in[10];
    const void* rel  = d_in[11];
    const void* fqrp = d_in[12];
    const void* fkrp = d_in[13];
    const void* fsvp = d_in[14];
    const void* fsvep= d_in[15];
    const int* fidx  = (const int*)d_in[16];

    float* W      = (float*)d_ws;
    float* musum  = W;            // 64
    float* gram   = W + 64;       // 4096
    float* sstat  = W + 4160;     // 48
    float* ostat  = W + 4208;     // 512   (zeroed region ends at 4720)
    float* weff   = W + 4720;     // 16384
    float* beff   = W + 21104;    // 256
    float* scoef  = W + 21360;    // 24
    float* ocoef  = W + 21384;    // 512
    int*   flag   = (int*)(W + 21896);    // 1 (+3 pad)
    u16*   qe     = (u16*)(W + 21900);    // 8*2304 u16  -> 9216 floats
    u16*   keT    = (u16*)(W + 31116);
    u16*   ve     = (u16*)(W + 40332);    // 16*2304 u16 -> ends at 58764
    float* fin    = W + 58764;            // 2304*128*48 f32 = 56.6 MB (optional)

    const size_t need_fin = ((size_t)58764 + 14155776) * 4;
    const int wmode = (ws_size >= need_fin) ? 1 : 2;

    k_detect<<<1, 256, 0, stream>>>((const u16*)X, flag);
    k_zero<<<8, 256, 0, stream>>>(W);
    k_emb<<<9, 256, 0, stream>>>(rel, fidx, flag, qe, keT, ve);
    k_gram<<<256, 256, 0, stream>>>(X, flag, musum, gram);
    k_fold<<<1, 256, 0, stream>>>(Wkv, Wq, gkv, bkv, gq, bq, flag, musum, gram, weff, beff);
    k_qkstat<<<2304, 256, 0, stream>>>(X, weff, beff, qe, keT, fqrp, fkrp, flag, sstat);
    k_simcoef<<<1, 32, 0, stream>>>(sstat, gsim, flag, scoef);
    k_attn<<<2304, 256, 0, stream>>>(X, weff, beff, qe, keT, ve, scoef, ocoef,
                                     fqrp, fkrp, fsvp, fsvep, flag, ostat, fin, d_out, 0);
    k_outcoef<<<1, 256, 0, stream>>>(ostat, gout, bout, flag, ocoef);
    k_attn<<<2304, 256, 0, stream>>>(X, weff, beff, qe, keT, ve, scoef, ocoef,
                                     fqrp, fkrp, fsvp, fsvep, flag, ostat, fin, d_out, wmode);
    if (wmode == 1) k_trans<<<dim3(128, 48), 256, 0, stream>>>(fin, flag, d_out);
}

// Round 4
// 1197.374 us; speedup vs baseline: 1.2588x; 1.2588x over previous
//
#include <hip/hip_runtime.h>

// RelativeAxialAttention on MI355X (gfx950). Single-attention-pass design.
// K=48, G=8, DK=8, DV=16, CIN=64, B = 2304. Inputs f32 (confirmed via FETCH_SIZE
// round 3) but runtime dtype detection kept for safety; internal compute f32.
//
// Math shortcuts:
//  * kv/q BatchNorm folded into GEMM weights via x-gram (y=Wx => mean=W.mu, E[y^2]=W M W^T).
//  * sim BN: mean & beta are per-(t,g) constants => softmax-invariant; only scales needed.
//  * attention computed ONCE: stage qkv bf16 -> stats pass (no z storage) ->
//    attn pass writes raw (sv,sve) pairs -> cheap BN+pairsum+transpose epilogue.
// Fast path needs 113.5 MB workspace; otherwise falls back to round-3 recompute design.

typedef unsigned short u16;

#define N_S 110592
#define N_B 2304

__device__ __forceinline__ float b2f(u16 v) {
    return __builtin_bit_cast(float, ((unsigned)v) << 16);
}
__device__ __forceinline__ u16 f2b(float f) {
    unsigned u = __builtin_bit_cast(unsigned, f);
    u = (u + 0x7FFFu + ((u >> 16) & 1u)) >> 16;
    return (u16)u;
}
__device__ __forceinline__ float ldf(const void* p, int idx, int f32) {
    return f32 ? ((const float*)p)[idx] : b2f(((const u16*)p)[idx]);
}

// ---------------- dtype detection: sample even u16 indices of X ----------------
__global__ void k_detect(const u16* X, int* flag) {
    __shared__ int tot;
    if (threadIdx.x == 0) tot = 0;
    __syncthreads();
    int cnt = 0;
#pragma unroll
    for (int k = 0; k < 8; k++) {
        u16 v = X[(threadIdx.x * 8 + k) * 2];
        int e = (v >> 7) & 0xFF;
        cnt += (e >= 0x70 && e <= 0x8F) ? 1 : 0;
    }
    atomicAdd(&tot, cnt);
    __syncthreads();
    if (threadIdx.x == 0) flag[0] = (tot < 1024) ? 1 : 0;   // 1 = f32
}

// ---------------- zero stats region ----------------
__global__ void k_zero(float* w) {
    for (int i = blockIdx.x * blockDim.x + threadIdx.x; i < 4720; i += gridDim.x * blockDim.x)
        w[i] = 0.0f;
}

// ---------------- build emb tables (bf16; keT pre-transposed) ----------------
__global__ void k_emb(const void* rel, const int* fidx, const int* flag,
                      u16* qe, u16* keT, u16* ve) {
    int f32 = flag[0];
    int t = blockIdx.x * 256 + threadIdx.x;
    if (t >= 2304) return;
    int i = t / 48, j = t % 48;
    int fij = fidx[i * 48 + j];
    int fji = fidx[j * 48 + i];
#pragma unroll
    for (int c = 0; c < 8; c++) {
        qe[c * 2304 + t]  = f2b(ldf(rel, c * 95 + fij, f32));
        keT[c * 2304 + t] = f2b(ldf(rel, (8 + c) * 95 + fji, f32));
    }
#pragma unroll
    for (int c = 0; c < 16; c++)
        ve[c * 2304 + t] = f2b(ldf(rel, (16 + c) * 95 + fij, f32));
}

// ---------------- x gram ----------------
__global__ __launch_bounds__(256) void k_gram(const void* Xv, const int* flag,
                                              float* musum, float* gram) {
    __shared__ float xs[64 * 65];
    int f32 = flag[0];
    int tid = threadIdx.x;
    int cb1 = tid >> 4, cb2 = tid & 15;
    float acc[4][4];
#pragma unroll
    for (int a = 0; a < 4; a++)
#pragma unroll
        for (int b = 0; b < 4; b++) acc[a][b] = 0.0f;
    float mur = 0.0f;
    for (int tile = blockIdx.x; tile < 1728; tile += gridDim.x) {
        int s0 = tile * 64;
        __syncthreads();
#pragma unroll
        for (int r = 0; r < 4; r++) {
            int idx4 = tid + 256 * r;
            int c = idx4 >> 4, sl = (idx4 & 15) * 4;
            if (f32) {
                float4 u = *(const float4*)((const float*)Xv + c * N_S + s0 + sl);
                xs[c * 65 + sl + 0] = u.x; xs[c * 65 + sl + 1] = u.y;
                xs[c * 65 + sl + 2] = u.z; xs[c * 65 + sl + 3] = u.w;
            } else {
                ushort4 u = *(const ushort4*)((const u16*)Xv + c * N_S + s0 + sl);
                xs[c * 65 + sl + 0] = b2f(u.x); xs[c * 65 + sl + 1] = b2f(u.y);
                xs[c * 65 + sl + 2] = b2f(u.z); xs[c * 65 + sl + 3] = b2f(u.w);
            }
        }
        __syncthreads();
        for (int s = 0; s < 64; s++) {
            float av[4], bv[4];
#pragma unroll
            for (int a = 0; a < 4; a++) av[a] = xs[(cb1 + 16 * a) * 65 + s];
#pragma unroll
            for (int b = 0; b < 4; b++) bv[b] = xs[(cb2 + 16 * b) * 65 + s];
#pragma unroll
            for (int a = 0; a < 4; a++)
#pragma unroll
                for (int b = 0; b < 4; b++) acc[a][b] += av[a] * bv[b];
        }
        if (tid < 64) {
            for (int s = 0; s < 64; s++) mur += xs[tid * 65 + s];
        }
    }
#pragma unroll
    for (int a = 0; a < 4; a++)
#pragma unroll
        for (int b = 0; b < 4; b++)
            atomicAdd(&gram[(cb1 + 16 * a) * 64 + (cb2 + 16 * b)], acc[a][b]);
    if (tid < 64) atomicAdd(&musum[tid], mur);
}

// ---------------- fold BN into weights ----------------
__global__ __launch_bounds__(256) void k_fold(const void* Wkv, const void* Wq,
        const void* gkv, const void* bkv, const void* gq, const void* bq,
        const int* flag, const float* musum, const float* gram,
        float* weff, float* beff) {
    int f32 = flag[0];
    int o = threadIdx.x;
    float gam, bet;
    float w[64];
    if (o < 192) {
#pragma unroll
        for (int c = 0; c < 64; c++) w[c] = ldf(Wkv, o * 64 + c, f32);
        gam = ldf(gkv, o, f32); bet = ldf(bkv, o, f32);
    } else {
        int oq = o - 192;
#pragma unroll
        for (int c = 0; c < 64; c++) w[c] = ldf(Wq, oq * 64 + c, f32);
        gam = ldf(gq, oq, f32); bet = ldf(bq, oq, f32);
    }
    const float inv = 1.0f / (float)N_S;
    float mean = 0.0f;
#pragma unroll
    for (int c = 0; c < 64; c++) mean += w[c] * musum[c];
    mean *= inv;
    float e2 = 0.0f;
    for (int c = 0; c < 64; c++) {
        float t = 0.0f;
#pragma unroll
        for (int c2 = 0; c2 < 64; c2++) t += w[c2] * gram[c * 64 + c2];
        e2 += w[c] * t;
    }
    e2 *= inv;
    float var = e2 - mean * mean;
    if (var < 0.0f) var = 0.0f;
    float sc = gam * rsqrtf(var + 1e-5f);
#pragma unroll
    for (int c = 0; c < 64; c++) weff[o * 64 + c] = sc * w[c];
    beff[o] = bet - sc * mean;
}

// ================= FAST PATH =================
// stage1: qkv GEMM -> ws bf16 (layout ((b*8+g)*32 + r)*48, r: 0-7 q, 8-15 k, 16-31 v)
//         + sim-BN stat accumulation from recomputed qk/qr/kr.
__global__ __launch_bounds__(256) void k_stage1(const void* Xv, const float* weff, const float* beff,
        const u16* qe, const u16* keT, const void* fqrp, const void* fkrp,
        const int* flag, float* sstat, u16* qkv) {
    __shared__ __align__(16) float xs[3072];    // [c][h]
    __shared__ __align__(16) float qk[6144];    // [g][q/k][8][48] : g*768 + t*384 + c*48 + h
    __shared__ float red[48];
    int f32 = flag[0];
    int b = blockIdx.x, tid = threadIdx.x;
    for (int idx = tid; idx < 3072; idx += 256) {
        int c = idx / 48, h = idx % 48;
        xs[idx] = ldf(Xv, c * N_S + h * 2304 + b, f32);
    }
    if (tid < 48) red[tid] = 0.0f;
    __syncthreads();
    {   // GEMM: one output row per thread
        int g = tid >> 5, r = tid & 31;
        int o;
        if (r < 8)       o = 192 + g * 8 + r;       // q
        else if (r < 16) o = g * 24 + (r - 8);      // k
        else             o = g * 24 + 8 + (r - 16); // v
        float wr[64];
        const float4* wrow = (const float4*)(weff + o * 64);
#pragma unroll
        for (int c4 = 0; c4 < 16; c4++) {
            float4 t4 = wrow[c4];
            wr[c4 * 4 + 0] = t4.x; wr[c4 * 4 + 1] = t4.y; wr[c4 * 4 + 2] = t4.z; wr[c4 * 4 + 3] = t4.w;
        }
        float bias = beff[o];
        u16* gdst = qkv + (b * 256 + tid) * 48;
        float* ldst = (r < 8) ? (qk + g * 768 + r * 48)
                    : (r < 16 ? (qk + g * 768 + 384 + (r - 8) * 48) : nullptr);
#pragma unroll
        for (int hb = 0; hb < 6; hb++) {
            float acc[8];
#pragma unroll
            for (int u = 0; u < 8; u++) acc[u] = bias;
#pragma unroll
            for (int c = 0; c < 64; c++) {
                float wv = wr[c];
                const float4* xp = (const float4*)(xs + c * 48 + hb * 8);
                float4 x0 = xp[0], x1 = xp[1];
                acc[0] += wv * x0.x; acc[1] += wv * x0.y; acc[2] += wv * x0.z; acc[3] += wv * x0.w;
                acc[4] += wv * x1.x; acc[5] += wv * x1.y; acc[6] += wv * x1.z; acc[7] += wv * x1.w;
            }
            ushort4 p0 = make_ushort4(f2b(acc[0]), f2b(acc[1]), f2b(acc[2]), f2b(acc[3]));
            ushort4 p1 = make_ushort4(f2b(acc[4]), f2b(acc[5]), f2b(acc[6]), f2b(acc[7]));
            *(ushort4*)(gdst + hb * 8)     = p0;
            *(ushort4*)(gdst + hb * 8 + 4) = p1;
            if (ldst) {
                *(float4*)(ldst + hb * 8)     = make_float4(acc[0], acc[1], acc[2], acc[3]);
                *(float4*)(ldst + hb * 8 + 4) = make_float4(acc[4], acc[5], acc[6], acc[7]);
            }
        }
    }
    __syncthreads();
    float fqr = ldf(fqrp, 0, f32), fkr = ldf(fkrp, 0, f32);
    float sum[24], sq[24];
#pragma unroll
    for (int k = 0; k < 24; k++) { sum[k] = 0.0f; sq[k] = 0.0f; }
    for (int r = 0; r < 3; r++) {
        int chunk = tid + 256 * r;
        if (chunk >= 576) break;
        int i = chunk / 12, j0 = (chunk % 12) * 4;
        float qv[8][4], kv[8][4];
#pragma unroll
        for (int c = 0; c < 8; c++) {
            ushort4 uq = *(const ushort4*)(qe + c * 2304 + i * 48 + j0);
            ushort4 uk = *(const ushort4*)(keT + c * 2304 + i * 48 + j0);
            qv[c][0] = b2f(uq.x); qv[c][1] = b2f(uq.y); qv[c][2] = b2f(uq.z); qv[c][3] = b2f(uq.w);
            kv[c][0] = b2f(uk.x); kv[c][1] = b2f(uk.y); kv[c][2] = b2f(uk.z); kv[c][3] = b2f(uk.w);
        }
#pragma unroll
        for (int g = 0; g < 8; g++) {
            float zq[4] = {0,0,0,0}, zr[4] = {0,0,0,0}, zk[4] = {0,0,0,0};
#pragma unroll
            for (int c = 0; c < 8; c++) {
                float qi = qk[g * 768 + c * 48 + i];
                float4 kk = *(const float4*)(qk + g * 768 + 384 + c * 48 + j0);
                zq[0] += qi * kk.x; zq[1] += qi * kk.y; zq[2] += qi * kk.z; zq[3] += qi * kk.w;
                zr[0] += qi * qv[c][0]; zr[1] += qi * qv[c][1]; zr[2] += qi * qv[c][2]; zr[3] += qi * qv[c][3];
                zk[0] += kk.x * kv[c][0]; zk[1] += kk.y * kv[c][1]; zk[2] += kk.z * kv[c][2]; zk[3] += kk.w * kv[c][3];
            }
#pragma unroll
            for (int u = 0; u < 4; u++) {
                float a = zq[u];        sum[g] += a;       sq[g] += a * a;
                float r1 = zr[u] * fqr; sum[8 + g] += r1;  sq[8 + g] += r1 * r1;
                float r2 = zk[u] * fkr; sum[16 + g] += r2; sq[16 + g] += r2 * r2;
            }
        }
    }
#pragma unroll
    for (int k = 0; k < 24; k++) {
        float s = sum[k], q = sq[k];
        for (int off = 32; off >= 1; off >>= 1) { s += __shfl_xor(s, off); q += __shfl_xor(q, off); }
        if ((tid & 63) == 0) { atomicAdd(&red[k], s); atomicAdd(&red[24 + k], q); }
    }
    __syncthreads();
    if (tid < 48) atomicAdd(&sstat[tid], red[tid]);
}

__global__ void k_simcoef(const float* sstat, const void* gsim, const int* flag, float* scoef) {
    int ch = threadIdx.x;
    if (ch >= 24) return;
    const float n = 2304.0f * 2304.0f;   // B*H*H
    float mean = sstat[ch] / n;
    float var = sstat[24 + ch] / n - mean * mean;
    if (var < 0.0f) var = 0.0f;
    scoef[ch] = ldf(gsim, ch, flag[0]) * rsqrtf(var + 1e-5f);
}

// attn2: one block per (b, g-pair). Reads qkv bf16, writes pre2 pairs + out stats.
__global__ __launch_bounds__(256) void k_attn2(const u16* qkv,
        const u16* qe, const u16* keT, const u16* ve,
        const float* scoef, const void* fqrp, const void* fkrp,
        const void* fsvp, const void* fsvep, const int* flag,
        float* ostat, u16* pre2) {
    __shared__ __align__(16) float qls[768];    // [gl][8][48] f32
    __shared__ __align__(16) u16 kls[768];      // [gl][8][48] bf16
    __shared__ __align__(16) u16 vls[1536];     // [gl][16][48] bf16
    __shared__ __align__(16) float z[4992];     // [gl][48][52]
    int f32 = flag[0];
    int b = blockIdx.x, g0 = blockIdx.y * 2, tid = threadIdx.x;
    {   // load qkv: 3072 u16 = 768 ushort4
        const u16* src = qkv + (b * 256 + g0 * 32) * 48;
#pragma unroll
        for (int rr = 0; rr < 3; rr++) {
            int idx = tid + 256 * rr;
            int ridx = idx / 12, hq = (idx % 12) * 4;
            ushort4 u = *(const ushort4*)(src + ridx * 48 + hq);
            int gl = ridx >> 5, r = ridx & 31;
            if (r < 8) {
                float* d = qls + gl * 384 + r * 48 + hq;
                d[0] = b2f(u.x); d[1] = b2f(u.y); d[2] = b2f(u.z); d[3] = b2f(u.w);
            } else if (r < 16) {
                *(ushort4*)(kls + gl * 384 + (r - 8) * 48 + hq) = u;
            } else {
                *(ushort4*)(vls + gl * 768 + (r - 16) * 48 + hq) = u;
            }
        }
    }
    __syncthreads();
    float fqr = ldf(fqrp, 0, f32), fkr = ldf(fkrp, 0, f32);
    float fsv = ldf(fsvp, 0, f32), fsve = ldf(fsvep, 0, f32);
    float c0a = scoef[g0],     c1a = scoef[8 + g0],     c2a = scoef[16 + g0];
    float c0b = scoef[g0 + 1], c1b = scoef[8 + g0 + 1], c2b = scoef[16 + g0 + 1];
    // logits for both heads, emb loaded once per (i,j0) chunk
    for (int r = 0; r < 3; r++) {
        int chunk = tid + 256 * r;
        if (chunk >= 576) break;
        int i = chunk / 12, j0 = (chunk % 12) * 4;
        float qv[8][4], kv[8][4];
#pragma unroll
        for (int c = 0; c < 8; c++) {
            ushort4 uq = *(const ushort4*)(qe + c * 2304 + i * 48 + j0);
            ushort4 uk = *(const ushort4*)(keT + c * 2304 + i * 48 + j0);
            qv[c][0] = b2f(uq.x); qv[c][1] = b2f(uq.y); qv[c][2] = b2f(uq.z); qv[c][3] = b2f(uq.w);
            kv[c][0] = b2f(uk.x); kv[c][1] = b2f(uk.y); kv[c][2] = b2f(uk.z); kv[c][3] = b2f(uk.w);
        }
#pragma unroll
        for (int gl = 0; gl < 2; gl++) {
            float c0 = gl ? c0b : c0a, c1 = gl ? c1b : c1a, c2 = gl ? c2b : c2a;
            float zq[4] = {0,0,0,0}, zr[4] = {0,0,0,0}, zk[4] = {0,0,0,0};
#pragma unroll
            for (int c = 0; c < 8; c++) {
                float qi = qls[gl * 384 + c * 48 + i];
                ushort4 ku = *(const ushort4*)(kls + gl * 384 + c * 48 + j0);
                float k0 = b2f(ku.x), k1 = b2f(ku.y), k2 = b2f(ku.z), k3 = b2f(ku.w);
                zq[0] += qi * k0; zq[1] += qi * k1; zq[2] += qi * k2; zq[3] += qi * k3;
                zr[0] += qi * qv[c][0]; zr[1] += qi * qv[c][1]; zr[2] += qi * qv[c][2]; zr[3] += qi * qv[c][3];
                zk[0] += k0 * kv[c][0]; zk[1] += k1 * kv[c][1]; zk[2] += k2 * kv[c][2]; zk[3] += k3 * kv[c][3];
            }
            float4 o4;
            o4.x = c0 * zq[0] + c1 * (fqr * zr[0]) + c2 * (fkr * zk[0]);
            o4.y = c0 * zq[1] + c1 * (fqr * zr[1]) + c2 * (fkr * zk[1]);
            o4.z = c0 * zq[2] + c1 * (fqr * zr[2]) + c2 * (fkr * zk[2]);
            o4.w = c0 * zq[3] + c1 * (fqr * zr[3]) + c2 * (fkr * zk[3]);
            *(float4*)(z + gl * 2496 + i * 52 + j0) = o4;
        }
    }
    __syncthreads();
    {   // softmax: 96 rows over 4 waves (24 each)
        int wv = tid >> 6, lane = tid & 63;
        int gl = wv >> 1, i0 = (wv & 1) * 24;
        for (int rr = 0; rr < 24; rr++) {
            int i = i0 + rr;
            float val = (lane < 48) ? z[gl * 2496 + i * 52 + lane] : -1e30f;
            float m = val;
            for (int off = 32; off >= 1; off >>= 1) m = fmaxf(m, __shfl_xor(m, off));
            float e = (lane < 48) ? __expf(val - m) : 0.0f;
            float s = e;
            for (int off = 32; off >= 1; off >>= 1) s += __shfl_xor(s, off);
            if (lane < 48) z[gl * 2496 + i * 52 + lane] = e / s;
        }
    }
    __syncthreads();
    {   // sv / sve: thread -> (gl, c, u); i in {u, u+8, ..., u+40}
        int gl = tid >> 7, c = (tid >> 3) & 15, u = tid & 7;
        int g = g0 + gl;
        float sumA = 0, sqA = 0, sumB = 0, sqB = 0;
#pragma unroll
        for (int rep = 0; rep < 6; rep++) {
            int i = u + 8 * rep;
            float sv = 0.0f, se = 0.0f;
#pragma unroll
            for (int j4 = 0; j4 < 12; j4++) {
                float4 sm = *(const float4*)(z + gl * 2496 + i * 52 + j4 * 4);
                ushort4 vu = *(const ushort4*)(vls + gl * 768 + c * 48 + j4 * 4);
                ushort4 eu = *(const ushort4*)(ve + c * 2304 + i * 48 + j4 * 4);
                sv += sm.x * b2f(vu.x) + sm.y * b2f(vu.y) + sm.z * b2f(vu.z) + sm.w * b2f(vu.w);
                se += sm.x * b2f(eu.x) + sm.y * b2f(eu.y) + sm.z * b2f(eu.z) + sm.w * b2f(eu.w);
            }
            float a = sv * fsv, bb = se * fsve;
            *(ushort2*)(pre2 + ((b * 128 + g * 16 + c) * 48 + i) * 2) = make_ushort2(f2b(a), f2b(bb));
            sumA += a; sqA += a * a; sumB += bb; sqB += bb * bb;
        }
#pragma unroll
        for (int off = 1; off <= 4; off <<= 1) {
            sumA += __shfl_xor(sumA, off); sqA += __shfl_xor(sqA, off);
            sumB += __shfl_xor(sumB, off); sqB += __shfl_xor(sqB, off);
        }
        if (u == 0) {
            int ch2 = g * 32 + c * 2;
            atomicAdd(&ostat[ch2 * 2 + 0], sumA);
            atomicAdd(&ostat[ch2 * 2 + 1], sqA);
            atomicAdd(&ostat[ch2 * 2 + 2], sumB);
            atomicAdd(&ostat[ch2 * 2 + 3], sqB);
        }
    }
}

__global__ void k_outcoef(const float* ostat, const void* gout, const void* bout,
                          const int* flag, float* ocoef) {
    int f32 = flag[0];
    int o = threadIdx.x;   // 256
    const float n = 110592.0f;
    float mean = ostat[o * 2] / n;
    float var = ostat[o * 2 + 1] / n - mean * mean;
    if (var < 0.0f) var = 0.0f;
    float sc = ldf(gout, o, f32) * rsqrtf(var + 1e-5f);
    ocoef[o * 2] = sc;
    ocoef[o * 2 + 1] = ldf(bout, o, f32) - mean * sc;
}

// final: BN + pair-sum + transpose. pre2[((b*128+ch)*48+i)*2 + {0,1}] -> out[ch][i][b]
__global__ __launch_bounds__(256) void k_final(const u16* pre2, const float* ocoef,
                                               const int* flag, void* outp) {
    __shared__ float tile[48 * 49];
    int f32 = flag[0];
    int ch = blockIdx.x, w = blockIdx.y, tid = threadIdx.x;
    float sc0 = ocoef[(ch * 2) * 2],     sh0 = ocoef[(ch * 2) * 2 + 1];
    float sc1 = ocoef[(ch * 2 + 1) * 2], sh1 = ocoef[(ch * 2 + 1) * 2 + 1];
    float shs = sh0 + sh1;
#pragma unroll
    for (int r = 0; r < 9; r++) {
        int idx = tid + 256 * r;
        int d = idx / 48, i = idx % 48;
        ushort2 p = ((const ushort2*)pre2)[((w * 48 + d) * 128 + ch) * 48 + i];
        tile[d * 49 + i] = b2f(p.x) * sc0 + b2f(p.y) * sc1 + shs;
    }
    __syncthreads();
#pragma unroll
    for (int r = 0; r < 9; r++) {
        int idx = tid + 256 * r;
        int i = idx / 48, d = idx % 48;
        float v = tile[d * 49 + i];
        int oidx = ch * N_S + i * 2304 + w * 48 + d;
        if (f32) ((float*)outp)[oidx] = v;
        else     ((u16*)outp)[oidx] = f2b(v);
    }
}

// ================= FALLBACK PATH (round-3 design, ws-slim) =================
__global__ __launch_bounds__(256) void k_qkstat(const void* Xv, const float* weff, const float* beff,
        const u16* qe, const u16* keT, const void* fqrp, const void* fkrp,
        const int* flag, float* sstat) {
    __shared__ __align__(16) float xs[3072];
    __shared__ __align__(16) float qsh[3072];
    __shared__ __align__(16) float ksh[3072];
    __shared__ float red[48];
    int f32 = flag[0];
    int b = blockIdx.x, tid = threadIdx.x;
    for (int idx = tid; idx < 3072; idx += 256) {
        int c = idx / 48, h = idx % 48;
        xs[idx] = ldf(Xv, c * N_S + h * 2304 + b, f32);
    }
    if (tid < 48) red[tid] = 0.0f;
    __syncthreads();
    {
        int r = tid >> 1, half = tid & 1;
        int o; float* dst;
        if (r < 64) { o = 192 + r; dst = qsh + r * 48; }
        else { int rk = r - 64; o = (rk >> 3) * 24 + (rk & 7); dst = ksh + rk * 48; }
        float wr[64];
        const float4* wrow = (const float4*)(weff + o * 64);
#pragma unroll
        for (int c4 = 0; c4 < 16; c4++) {
            float4 t4 = wrow[c4];
            wr[c4 * 4 + 0] = t4.x; wr[c4 * 4 + 1] = t4.y; wr[c4 * 4 + 2] = t4.z; wr[c4 * 4 + 3] = t4.w;
        }
        float bias = beff[o];
        int h0 = half * 24;
#pragma unroll
        for (int hb = 0; hb < 3; hb++) {
            float acc[8];
#pragma unroll
            for (int u = 0; u < 8; u++) acc[u] = bias;
#pragma unroll
            for (int c = 0; c < 64; c++) {
                float wv = wr[c];
                const float4* xp = (const float4*)(xs + c * 48 + h0 + hb * 8);
                float4 x0 = xp[0], x1 = xp[1];
                acc[0] += wv * x0.x; acc[1] += wv * x0.y; acc[2] += wv * x0.z; acc[3] += wv * x0.w;
                acc[4] += wv * x1.x; acc[5] += wv * x1.y; acc[6] += wv * x1.z; acc[7] += wv * x1.w;
            }
            *(float4*)(dst + h0 + hb * 8)     = make_float4(acc[0], acc[1], acc[2], acc[3]);
            *(float4*)(dst + h0 + hb * 8 + 4) = make_float4(acc[4], acc[5], acc[6], acc[7]);
        }
    }
    __syncthreads();
    float fqr = ldf(fqrp, 0, f32), fkr = ldf(fkrp, 0, f32);
    float sum[24], sq[24];
#pragma unroll
    for (int k = 0; k < 24; k++) { sum[k] = 0.0f; sq[k] = 0.0f; }
    for (int r = 0; r < 3; r++) {
        int chunk = tid + 256 * r;
        if (chunk >= 576) break;
        int i = chunk / 12, j0 = (chunk % 12) * 4;
        float qv[8][4], kv[8][4];
#pragma unroll
        for (int c = 0; c < 8; c++) {
            ushort4 uq = *(const ushort4*)(qe + c * 2304 + i * 48 + j0);
            ushort4 uk = *(const ushort4*)(keT + c * 2304 + i * 48 + j0);
            qv[c][0] = b2f(uq.x); qv[c][1] = b2f(uq.y); qv[c][2] = b2f(uq.z); qv[c][3] = b2f(uq.w);
            kv[c][0] = b2f(uk.x); kv[c][1] = b2f(uk.y); kv[c][2] = b2f(uk.z); kv[c][3] = b2f(uk.w);
        }
#pragma unroll
        for (int g = 0; g < 8; g++) {
            float zq[4] = {0,0,0,0}, zr[4] = {0,0,0,0}, zk[4] = {0,0,0,0};
#pragma unroll
            for (int c = 0; c < 8; c++) {
                float qi = qsh[(g * 8 + c) * 48 + i];
                float4 kk = *(const float4*)(ksh + (g * 8 + c) * 48 + j0);
                zq[0] += qi * kk.x; zq[1] += qi * kk.y; zq[2] += qi * kk.z; zq[3] += qi * kk.w;
                zr[0] += qi * qv[c][0]; zr[1] += qi * qv[c][1]; zr[2] += qi * qv[c][2]; zr[3] += qi * qv[c][3];
                zk[0] += kk.x * kv[c][0]; zk[1] += kk.y * kv[c][1]; zk[2] += kk.z * kv[c][2]; zk[3] += kk.w * kv[c][3];
            }
#pragma unroll
            for (int u = 0; u < 4; u++) {
                float a = zq[u];        sum[g] += a;       sq[g] += a * a;
                float r1 = zr[u] * fqr; sum[8 + g] += r1;  sq[8 + g] += r1 * r1;
                float r2 = zk[u] * fkr; sum[16 + g] += r2; sq[16 + g] += r2 * r2;
            }
        }
    }
#pragma unroll
    for (int k = 0; k < 24; k++) {
        float s = sum[k], q = sq[k];
        for (int off = 32; off >= 1; off >>= 1) { s += __shfl_xor(s, off); q += __shfl_xor(q, off); }
        if ((tid & 63) == 0) { atomicAdd(&red[k], s); atomicAdd(&red[24 + k], q); }
    }
    __syncthreads();
    if (tid < 48) atomicAdd(&sstat[tid], red[tid]);
}

// fallback attention: mode 0 = stats, mode 2 = scattered direct out
__global__ __launch_bounds__(256) void k_attn(const void* Xv, const float* weff, const float* beff,
        const u16* qe, const u16* keT, const u16* ve,
        const float* scoef, const float* ocoef,
        const void* fqrp, const void* fkrp, const void* fsvp, const void* fsvep,
        const int* flag, float* ostat, void* outp, int mode) {
    __shared__ __align__(16) float zx[3072];
    __shared__ __align__(16) float qsh[3072];
    __shared__ __align__(16) float ksh[3072];
    __shared__ __align__(16) float vsh[6144];
    __shared__ float osl[512];
    int f32 = flag[0];
    int b = blockIdx.x, tid = threadIdx.x;
    for (int idx = tid; idx < 3072; idx += 256) {
        int c = idx / 48, h = idx % 48;
        zx[idx] = ldf(Xv, c * N_S + h * 2304 + b, f32);
    }
    __syncthreads();
    {
        int o; float* dst;
        if (tid < 64)       { o = 192 + tid; dst = qsh + tid * 48; }
        else if (tid < 128) { int rk = tid - 64; o = (rk >> 3) * 24 + (rk & 7); dst = ksh + rk * 48; }
        else                { int rv = tid - 128; o = (rv >> 4) * 24 + 8 + (rv & 15); dst = vsh + rv * 48; }
        float wr[64];
        const float4* wrow = (const float4*)(weff + o * 64);
#pragma unroll
        for (int c4 = 0; c4 < 16; c4++) {
            float4 t4 = wrow[c4];
            wr[c4 * 4 + 0] = t4.x; wr[c4 * 4 + 1] = t4.y; wr[c4 * 4 + 2] = t4.z; wr[c4 * 4 + 3] = t4.w;
        }
        float bias = beff[o];
#pragma unroll
        for (int hb = 0; hb < 6; hb++) {
            float acc[8];
#pragma unroll
            for (int u = 0; u < 8; u++) acc[u] = bias;
#pragma unroll
            for (int c = 0; c < 64; c++) {
                float wv = wr[c];
                const float4* xp = (const float4*)(zx + c * 48 + hb * 8);
                float4 x0 = xp[0], x1 = xp[1];
                acc[0] += wv * x0.x; acc[1] += wv * x0.y; acc[2] += wv * x0.z; acc[3] += wv * x0.w;
                acc[4] += wv * x1.x; acc[5] += wv * x1.y; acc[6] += wv * x1.z; acc[7] += wv * x1.w;
            }
            *(float4*)(dst + hb * 8)     = make_float4(acc[0], acc[1], acc[2], acc[3]);
            *(float4*)(dst + hb * 8 + 4) = make_float4(acc[4], acc[5], acc[6], acc[7]);
        }
    }
    __syncthreads();
    float fqr = ldf(fqrp, 0, f32), fkr = ldf(fkrp, 0, f32);
    float fsv = ldf(fsvp, 0, f32), fsve = ldf(fsvep, 0, f32);
    float* z = zx;
    for (int g = 0; g < 8; g++) {
        float c0 = scoef[g], c1 = scoef[8 + g], c2 = scoef[16 + g];
        for (int r = 0; r < 3; r++) {
            int chunk = tid + 256 * r;
            if (chunk >= 576) break;
            int i = chunk / 12, j0 = (chunk % 12) * 4;
            float zq[4] = {0,0,0,0}, zr[4] = {0,0,0,0}, zk[4] = {0,0,0,0};
#pragma unroll
            for (int c = 0; c < 8; c++) {
                ushort4 uq = *(const ushort4*)(qe + c * 2304 + i * 48 + j0);
                ushort4 uk = *(const ushort4*)(keT + c * 2304 + i * 48 + j0);
                float qi = qsh[(g * 8 + c) * 48 + i];
                float4 kk = *(const float4*)(ksh + (g * 8 + c) * 48 + j0);
                zq[0] += qi * kk.x; zq[1] += qi * kk.y; zq[2] += qi * kk.z; zq[3] += qi * kk.w;
                zr[0] += qi * b2f(uq.x); zr[1] += qi * b2f(uq.y); zr[2] += qi * b2f(uq.z); zr[3] += qi * b2f(uq.w);
                zk[0] += kk.x * b2f(uk.x); zk[1] += kk.y * b2f(uk.y); zk[2] += kk.z * b2f(uk.z); zk[3] += kk.w * b2f(uk.w);
            }
            float4 o4;
            o4.x = c0 * zq[0] + c1 * (fqr * zr[0]) + c2 * (fkr * zk[0]);
            o4.y = c0 * zq[1] + c1 * (fqr * zr[1]) + c2 * (fkr * zk[1]);
            o4.z = c0 * zq[2] + c1 * (fqr * zr[2]) + c2 * (fkr * zk[2]);
            o4.w = c0 * zq[3] + c1 * (fqr * zr[3]) + c2 * (fkr * zk[3]);
            *(float4*)(z + i * 52 + j0) = o4;
        }
        __syncthreads();
        {
            int wv = tid >> 6, lane = tid & 63;
            for (int rr = 0; rr < 12; rr++) {
                int i = wv * 12 + rr;
                float val = (lane < 48) ? z[i * 52 + lane] : -1e30f;
                float m = val;
                for (int off = 32; off >= 1; off >>= 1) m = fmaxf(m, __shfl_xor(m, off));
                float e = (lane < 48) ? __expf(val - m) : 0.0f;
                float s = e;
                for (int off = 32; off >= 1; off >>= 1) s += __shfl_xor(s, off);
                if (lane < 48) z[i * 52 + lane] = e / s;
            }
        }
        __syncthreads();
        {
            int c = tid >> 4, u = tid & 15;
            int ch2 = g * 32 + c * 2;
            float oc0 = 0, oc1 = 0, osh = 0;
            if (mode != 0) {
                oc0 = ocoef[ch2 * 2]; oc1 = ocoef[(ch2 + 1) * 2];
                osh = ocoef[ch2 * 2 + 1] + ocoef[(ch2 + 1) * 2 + 1];
            }
            float sumA = 0, sqA = 0, sumB = 0, sqB = 0;
#pragma unroll
            for (int r = 0; r < 3; r++) {
                int i = u + 16 * r;
                float sv = 0.0f, se = 0.0f;
#pragma unroll
                for (int j4 = 0; j4 < 12; j4++) {
                    float4 sm = *(const float4*)(z + i * 52 + j4 * 4);
                    float4 vv = *(const float4*)(vsh + (g * 16 + c) * 48 + j4 * 4);
                    ushort4 veu = *(const ushort4*)(ve + c * 2304 + i * 48 + j4 * 4);
                    sv += sm.x * vv.x + sm.y * vv.y + sm.z * vv.z + sm.w * vv.w;
                    se += sm.x * b2f(veu.x) + sm.y * b2f(veu.y) + sm.z * b2f(veu.z) + sm.w * b2f(veu.w);
                }
                float a = sv * fsv, bb = se * fsve;
                if (mode == 0) {
                    sumA += a; sqA += a * a; sumB += bb; sqB += bb * bb;
                } else {
                    float outv = a * oc0 + bb * oc1 + osh;
                    int oidx = (g * 16 + c) * N_S + i * 2304 + b;
                    if (f32) ((float*)outp)[oidx] = outv;
                    else     ((u16*)outp)[oidx] = f2b(outv);
                }
            }
            if (mode == 0) {
                for (int off = 1; off <= 8; off <<= 1) {
                    sumA += __shfl_xor(sumA, off); sqA += __shfl_xor(sqA, off);
                    sumB += __shfl_xor(sumB, off); sqB += __shfl_xor(sqB, off);
                }
                if (u == 0) {
                    int base = ch2 * 2;
                    osl[base + 0] = sumA; osl[base + 1] = sqA;
                    osl[base + 2] = sumB; osl[base + 3] = sqB;
                }
            }
        }
        __syncthreads();
    }
    if (mode == 0) {
        atomicAdd(&ostat[tid], osl[tid]);
        atomicAdd(&ostat[tid + 256], osl[tid + 256]);
    }
}

extern "C" void kernel_launch(void* const* d_in, const int* in_sizes, int n_in,
                              void* d_out, int out_size, void* d_ws, size_t ws_size,
                              hipStream_t stream) {
    const void* X    = d_in[0];
    const void* Wkv  = d_in[1];
    const void* Wq   = d_in[2];
    const void* gkv  = d_in[3];
    const void* bkv  = d_in[4];
    const void* gq   = d_in[5];
    const void* bq   = d_in[6];
    const void* gsim = d_in[7];
    // d_in[8] (b_sim) unused: additive per-channel constant, softmax-invariant.
    const void* gout = d_in[9];
    const void* bout = d_in[10];
    const void* rel  = d_in[11];
    const void* fqrp = d_in[12];
    const void* fkrp = d_in[13];
    const void* fsvp = d_in[14];
    const void* fsvep= d_in[15];
    const int* fidx  = (const int*)d_in[16];

    float* W      = (float*)d_ws;
    float* musum  = W;            // 64
    float* gram   = W + 64;       // 4096
    float* sstat  = W + 4160;     // 48
    float* ostat  = W + 4208;     // 512  (zeroed region ends at 4720)
    float* weff   = W + 4720;     // 16384
    float* beff   = W + 21104;    // 256
    float* scoef  = W + 21360;    // 24
    float* ocoef  = W + 21384;    // 512
    int*   flag   = (int*)(W + 21896);    // 1 (+3 pad)
    u16*   qe     = (u16*)(W + 21900);    // 8*2304 u16
    u16*   keT    = (u16*)(W + 31116);
    u16*   ve     = (u16*)(W + 40332);    // ends at float offset 58764
    u16*   qkv    = (u16*)(W + 58764);    // 2304*256*48 bf16 = 56.6 MB
    u16*   pre2   = qkv + 28311552;       // 2304*128*48*2 bf16 = 56.6 MB

    const size_t need_fast = (size_t)58764 * 4 + 2ULL * 56623104ULL;  // 113.5 MB
    const int fast = (ws_size >= need_fast) ? 1 : 0;

    k_detect<<<1, 256, 0, stream>>>((const u16*)X, flag);
    k_zero<<<8, 256, 0, stream>>>(W);
    k_emb<<<9, 256, 0, stream>>>(rel, fidx, flag, qe, keT, ve);
    k_gram<<<256, 256, 0, stream>>>(X, flag, musum, gram);
    k_fold<<<1, 256, 0, stream>>>(Wkv, Wq, gkv, bkv, gq, bq, flag, musum, gram, weff, beff);
    if (fast) {
        k_stage1<<<2304, 256, 0, stream>>>(X, weff, beff, qe, keT, fqrp, fkrp, flag, sstat, qkv);
        k_simcoef<<<1, 32, 0, stream>>>(sstat, gsim, flag, scoef);
        k_attn2<<<dim3(2304, 4), 256, 0, stream>>>(qkv, qe, keT, ve, scoef,
                                                   fqrp, fkrp, fsvp, fsvep, flag, ostat, pre2);
        k_outcoef<<<1, 256, 0, stream>>>(ostat, gout, bout, flag, ocoef);
        k_final<<<dim3(128, 48), 256, 0, stream>>>(pre2, ocoef, flag, d_out);
    } else {
        k_qkstat<<<2304, 256, 0, stream>>>(X, weff, beff, qe, keT, fqrp, fkrp, flag, sstat);
        k_simcoef<<<1, 32, 0, stream>>>(sstat, gsim, flag, scoef);
        k_attn<<<2304, 256, 0, stream>>>(X, weff, beff, qe, keT, ve, scoef, ocoef,
                                         fqrp, fkrp, fsvp, fsvep, flag, ostat, d_out, 0);
        k_outcoef<<<1, 256, 0, stream>>>(ostat, gout, bout, flag, ocoef);
        k_attn<<<2304, 256, 0, stream>>>(X, weff, beff, qe, keT, ve, scoef, ocoef,
                                         fqrp, fkrp, fsvp, fsvep, flag, ostat, d_out, 2);
    }
}